// Round 3
// baseline (1044.219 us; speedup 1.0000x reference)
//
#include <hip/hip_runtime.h>
#include <hip/hip_bf16.h>

// E71 Delta cell: T=2048, B=16, D=1024, N=128
// proj layout in ws: [t][b][512] f32, cols 0..127=k_hat (after norm pass),
// 128..255=v, 256..383=q, 384..511=bx

#define T_STEPS 2048
#define NB 16
#define ND 128
#define KD 1024
#define PSTRIDE 512

typedef __attribute__((ext_vector_type(4))) float f32x4;
typedef __attribute__((ext_vector_type(2))) float f32x2;
typedef __attribute__((ext_vector_type(8))) short short8v;

__device__ __forceinline__ unsigned short f2bf(float f) {
  union { float f; unsigned int u; } c; c.f = f;
  unsigned int u = c.u;
  unsigned int r = u + 0x7fffu + ((u >> 16) & 1u);   // round-to-nearest-even
  return (unsigned short)(r >> 16);
}

// ---------------------------------------------------------------------------
// Projection GEMM (unchanged, ~56us): bf16 MFMA, 128x128 tile, BK=64,
// XOR-swizzled LDS.
// ---------------------------------------------------------------------------
__global__ __launch_bounds__(256) void proj_gemm(
    const float* __restrict__ X,
    const float* __restrict__ Wk, const float* __restrict__ Wv,
    const float* __restrict__ Wq, const float* __restrict__ Wb,
    float* __restrict__ C)
{
  __shared__ unsigned short As[128 * 64];
  __shared__ unsigned short Bs[128 * 64];
  const int tid = threadIdx.x;
  const int bm = blockIdx.x;
  const int bn = blockIdx.y;
  const float* W = (bn == 0) ? Wk : ((bn == 1) ? Wv : ((bn == 2) ? Wq : Wb));
  const int lane = tid & 63;
  const int wave = tid >> 6;
  const int wr = wave >> 1, wc = wave & 1;

  f32x4 acc[4][4];
#pragma unroll
  for (int i = 0; i < 4; i++)
#pragma unroll
    for (int j = 0; j < 4; j++) acc[i][j] = (f32x4){0.f, 0.f, 0.f, 0.f};

  for (int k0 = 0; k0 < KD; k0 += 64) {
    __syncthreads();
#pragma unroll
    for (int c = 0; c < 4; c++) {
      const int g = tid + c * 256;
      const int row = g >> 3;
      const int ch = g & 7;
      const int pos = ((ch ^ (row & 7)) * 8);
      {
        const float* ga = X + (size_t)(bm * 128 + row) * KD + k0 + ch * 8;
        float4 f0 = *(const float4*)(ga);
        float4 f1 = *(const float4*)(ga + 4);
        union { unsigned short u[8]; short8v v; } pk2;
        pk2.u[0] = f2bf(f0.x); pk2.u[1] = f2bf(f0.y);
        pk2.u[2] = f2bf(f0.z); pk2.u[3] = f2bf(f0.w);
        pk2.u[4] = f2bf(f1.x); pk2.u[5] = f2bf(f1.y);
        pk2.u[6] = f2bf(f1.z); pk2.u[7] = f2bf(f1.w);
        *reinterpret_cast<short8v*>(&As[row * 64 + pos]) = pk2.v;
      }
      {
        const float* gb = W + (size_t)row * KD + k0 + ch * 8;
        float4 f0 = *(const float4*)(gb);
        float4 f1 = *(const float4*)(gb + 4);
        union { unsigned short u[8]; short8v v; } pk2;
        pk2.u[0] = f2bf(f0.x); pk2.u[1] = f2bf(f0.y);
        pk2.u[2] = f2bf(f0.z); pk2.u[3] = f2bf(f0.w);
        pk2.u[4] = f2bf(f1.x); pk2.u[5] = f2bf(f1.y);
        pk2.u[6] = f2bf(f1.z); pk2.u[7] = f2bf(f1.w);
        *reinterpret_cast<short8v*>(&Bs[row * 64 + pos]) = pk2.v;
      }
    }
    __syncthreads();
#pragma unroll
    for (int kk = 0; kk < 2; kk++) {
      const int ch = kk * 4 + (lane >> 4);
      short8v a[4], b[4];
#pragma unroll
      for (int i = 0; i < 4; i++) {
        const int ar = wr * 64 + i * 16 + (lane & 15);
        a[i] = *reinterpret_cast<const short8v*>(&As[ar * 64 + ((ch ^ (ar & 7)) * 8)]);
        const int br = wc * 64 + i * 16 + (lane & 15);
        b[i] = *reinterpret_cast<const short8v*>(&Bs[br * 64 + ((ch ^ (br & 7)) * 8)]);
      }
#pragma unroll
      for (int i = 0; i < 4; i++)
#pragma unroll
        for (int j = 0; j < 4; j++)
          acc[i][j] = __builtin_amdgcn_mfma_f32_16x16x32_bf16(a[i], b[j], acc[i][j], 0, 0, 0);
    }
  }
#pragma unroll
  for (int i = 0; i < 4; i++)
#pragma unroll
    for (int j = 0; j < 4; j++)
#pragma unroll
      for (int r = 0; r < 4; r++) {
        const int row = bm * 128 + wr * 64 + i * 16 + (lane >> 4) * 4 + r;
        const int col = bn * 128 + wc * 64 + j * 16 + (lane & 15);
        C[(size_t)row * PSTRIDE + col] = acc[i][j][r];
      }
}

// ---------------------------------------------------------------------------
// k-normalization pre-pass: proj[row][0:128] <- k / (||k|| + eps).
// ---------------------------------------------------------------------------
__global__ __launch_bounds__(256) void norm_k(float* __restrict__ proj) {
  const int lane = threadIdx.x & 63;
  const int wid = (blockIdx.x * 256 + threadIdx.x) >> 6;
  float* rowp = proj + (size_t)wid * PSTRIDE;
  float2 kv = *reinterpret_cast<float2*>(rowp + lane * 2);
  float ss = kv.x * kv.x + kv.y * kv.y;
  ss += __shfl_xor(ss, 1);
  ss += __shfl_xor(ss, 2);
  ss += __shfl_xor(ss, 4);
  ss += __shfl_xor(ss, 8);
  ss += __shfl_xor(ss, 16);
  ss += __shfl_xor(ss, 32);
  const float rn = 1.0f / (sqrtf(ss) + 1e-6f);
  kv.x *= rn; kv.y *= rn;
  *reinterpret_cast<float2*>(rowp + lane * 2) = kv;
}

// ---------------------------------------------------------------------------
// Sequential scan. One wave per (batch, 8-row group); 256 single-wave blocks.
// 8-slot LDS ring staged by global_load_lds (un-sinkable async DMA), manual
// s_waitcnt vmcnt; LDS->reg fragments double-buffered one step ahead.
// Reductions: 2x DPP quad_perm + 1x ds_swizzle (xor4) over 8-lane groups.
// All dots/updates in float2 -> v_pk_fma_f32.
// ---------------------------------------------------------------------------
#define DEPTH 8

__device__ __forceinline__ float sum8(float v) {
  int i = __float_as_int(v);
  v += __int_as_float(__builtin_amdgcn_update_dpp(0, i, 0xB1, 0xF, 0xF, true));  // xor 1
  i = __float_as_int(v);
  v += __int_as_float(__builtin_amdgcn_update_dpp(0, i, 0x4E, 0xF, 0xF, true));  // xor 2
  v += __int_as_float(__builtin_amdgcn_ds_swizzle(__float_as_int(v), 0x101F));   // xor 4
  return v;
}

struct Buf {
  f32x2 kn[8]; f32x2 q[8]; float v, bxbb;
};

__global__ __launch_bounds__(64) void scan_kernel(
    const float* __restrict__ proj, const float* __restrict__ S_in,
    const float* __restrict__ d_beta, const float* __restrict__ b_beta,
    float* __restrict__ out, float* __restrict__ S_out)
{
  __shared__ float ring[DEPTH][PSTRIDE];   // 16 KB

  const int lane = threadIdx.x & 63;
  const int batch = blockIdx.x & 15;       // batches b, b+8 share XCD b%8
  const int wv = blockIdx.x >> 4;
  const int rloc = lane >> 3;
  const int row = wv * 8 + rloc;
  const int cblk = lane & 7;
  const int c0 = cblk * 16;

  f32x2 S2[8];
  {
    const float4* Sp4 = reinterpret_cast<const float4*>(
        S_in + ((size_t)batch * ND + row) * ND + c0);
#pragma unroll
    for (int j = 0; j < 4; j++) {
      float4 s4 = Sp4[j];
      S2[2 * j + 0] = (f32x2){s4.x, s4.y};
      S2[2 * j + 1] = (f32x2){s4.z, s4.w};
    }
  }
  const float db = d_beta[row];
  const float bb = b_beta[row];

  const float* pb = proj + (size_t)batch * PSTRIDE;
  const size_t sstep = (size_t)NB * PSTRIDE;
  float* outp = out + (size_t)batch * ND + row;
  const size_t ostep = (size_t)NB * ND;

  // --- staging helper: 2x 16B/lane global_load_lds = full 2KB row ---
#define STAGE(tt)                                                              \
  do {                                                                         \
    const int _s = (tt) & (DEPTH - 1);                                         \
    const float* _g = pb + (size_t)(tt) * sstep + lane * 4;                    \
    __builtin_amdgcn_global_load_lds(                                          \
        (const __attribute__((address_space(1))) void*)(_g),                   \
        (__attribute__((address_space(3))) void*)(&ring[_s][0]), 16, 0, 0);    \
    __builtin_amdgcn_global_load_lds(                                          \
        (const __attribute__((address_space(1))) void*)(_g + 256),             \
        (__attribute__((address_space(3))) void*)(&ring[_s][256]), 16, 0, 0);  \
  } while (0)

#define LOADBUF(tt, B)                                                         \
  do {                                                                         \
    const float* _sl = &ring[(tt) & (DEPTH - 1)][0];                           \
    const float4* _s4 = reinterpret_cast<const float4*>(_sl);                  \
    _Pragma("unroll")                                                          \
    for (int j = 0; j < 4; j++) {                                              \
      float4 a = _s4[cblk * 4 + j];                                            \
      (B).kn[2 * j + 0] = (f32x2){a.x, a.y};                                   \
      (B).kn[2 * j + 1] = (f32x2){a.z, a.w};                                   \
      float4 b = _s4[64 + cblk * 4 + j];                                       \
      (B).q[2 * j + 0] = (f32x2){b.x, b.y};                                    \
      (B).q[2 * j + 1] = (f32x2){b.z, b.w};                                    \
    }                                                                          \
    (B).v = _sl[128 + row];                                                    \
    (B).bxbb = _sl[384 + row] + bb;                                            \
  } while (0)

#define DOSTEP(B)                                                              \
  do {                                                                         \
    f32x2 acc = (f32x2){0.f, 0.f};                                             \
    _Pragma("unroll")                                                          \
    for (int j = 0; j < 8; j++) acc = __builtin_elementwise_fma(S2[j], (B).kn[j], acc); \
    const float r = sum8(acc.x + acc.y);                                       \
    const float vmr = (B).v - r;                                               \
    const float lg = fmaf(db, r, (B).bxbb);                                    \
    const float beta = 1.0f / (1.0f + __expf(-lg));                            \
    const float cr = beta * vmr;                                               \
    const f32x2 cr2 = (f32x2){cr, cr};                                         \
    f32x2 acco = (f32x2){0.f, 0.f};                                            \
    _Pragma("unroll")                                                          \
    for (int j = 0; j < 8; j++) {                                              \
      S2[j] = __builtin_elementwise_fma(cr2, (B).kn[j], S2[j]);                \
      acco = __builtin_elementwise_fma(S2[j], (B).q[j], acco);                 \
    }                                                                          \
    const float od = sum8(acco.x + acco.y);                                    \
    const float sg = 1.0f / (1.0f + __expf(-od));                              \
    if (cblk == 0) *outp = od * od * sg;                                       \
    outp += ostep;                                                             \
  } while (0)

#define WAITV asm volatile("s_waitcnt vmcnt(12)" ::: "memory")

  // prologue: fill ring, load step-0 fragments
#pragma unroll
  for (int s = 0; s < DEPTH; ++s) STAGE(s);
  WAITV;                       // slots 0 and 1 guaranteed (ops-after <= 12)
  Buf A, B;
  LOADBUF(0, A);

  for (int t = 0; t < T_STEPS; t += 2) {
    WAITV;
    LOADBUF(t + 1, B);                         // t+1 <= 2047 always
    DOSTEP(A);                                 // step t
    if (t + DEPTH < T_STEPS) STAGE(t + DEPTH);
    WAITV;
    if (t + 2 < T_STEPS) LOADBUF(t + 2, A);
    DOSTEP(B);                                 // step t+1
    if (t + DEPTH + 1 < T_STEPS) STAGE(t + DEPTH + 1);
  }

  {
    float4* So4 = reinterpret_cast<float4*>(
        S_out + ((size_t)batch * ND + row) * ND + c0);
#pragma unroll
    for (int j = 0; j < 4; j++) {
      float4 s4;
      s4.x = S2[2 * j + 0].x; s4.y = S2[2 * j + 0].y;
      s4.z = S2[2 * j + 1].x; s4.w = S2[2 * j + 1].y;
      So4[j] = s4;
    }
  }
#undef STAGE
#undef LOADBUF
#undef DOSTEP
#undef WAITV
}

extern "C" void kernel_launch(void* const* d_in, const int* in_sizes, int n_in,
                              void* d_out, int out_size, void* d_ws, size_t ws_size,
                              hipStream_t stream) {
  const float* x  = (const float*)d_in[0];   // [2048][16][1024]
  const float* S0 = (const float*)d_in[1];   // [16][128][128]
  const float* Wk = (const float*)d_in[2];
  const float* Wv = (const float*)d_in[3];
  const float* Wq = (const float*)d_in[4];
  const float* Wb = (const float*)d_in[5];
  const float* db = (const float*)d_in[6];
  const float* bb = (const float*)d_in[7];
  float* out  = (float*)d_out;                           // [2048][16][128]
  float* Sout = out + (size_t)T_STEPS * NB * ND;         // [16][128][128]
  float* proj = (float*)d_ws;                            // [32768][512] = 64 MB

  dim3 ggrid(256, 4);
  proj_gemm<<<ggrid, 256, 0, stream>>>(x, Wk, Wv, Wq, Wb, proj);
  norm_k<<<8192, 256, 0, stream>>>(proj);
  scan_kernel<<<256, 64, 0, stream>>>(proj, S0, db, bb, out, Sout);
}

// Round 4
// 488.403 us; speedup vs baseline: 2.1380x; 2.1380x over previous
//
#include <hip/hip_runtime.h>
#include <hip/hip_bf16.h>

// E71 Delta cell: T=2048, B=16, D=1024, N=128
// proj layout in ws: [t][b][512] f32, cols 0..127=k_hat (after norm pass),
// 128..255=v, 256..383=q, 384..511=bx

#define T_STEPS 2048
#define NB 16
#define ND 128
#define KD 1024
#define PSTRIDE 512

typedef __attribute__((ext_vector_type(4))) float f32x4;
typedef __attribute__((ext_vector_type(8))) short short8v;

__device__ __forceinline__ unsigned short f2bf(float f) {
  union { float f; unsigned int u; } c; c.f = f;
  unsigned int u = c.u;
  unsigned int r = u + 0x7fffu + ((u >> 16) & 1u);   // round-to-nearest-even
  return (unsigned short)(r >> 16);
}

// ---------------------------------------------------------------------------
// Projection GEMM (unchanged, ~56us): bf16 MFMA, 128x128 tile, BK=64,
// XOR-swizzled LDS.
// ---------------------------------------------------------------------------
__global__ __launch_bounds__(256) void proj_gemm(
    const float* __restrict__ X,
    const float* __restrict__ Wk, const float* __restrict__ Wv,
    const float* __restrict__ Wq, const float* __restrict__ Wb,
    float* __restrict__ C)
{
  __shared__ unsigned short As[128 * 64];
  __shared__ unsigned short Bs[128 * 64];
  const int tid = threadIdx.x;
  const int bm = blockIdx.x;
  const int bn = blockIdx.y;
  const float* W = (bn == 0) ? Wk : ((bn == 1) ? Wv : ((bn == 2) ? Wq : Wb));
  const int lane = tid & 63;
  const int wave = tid >> 6;
  const int wr = wave >> 1, wc = wave & 1;

  f32x4 acc[4][4];
#pragma unroll
  for (int i = 0; i < 4; i++)
#pragma unroll
    for (int j = 0; j < 4; j++) acc[i][j] = (f32x4){0.f, 0.f, 0.f, 0.f};

  for (int k0 = 0; k0 < KD; k0 += 64) {
    __syncthreads();
#pragma unroll
    for (int c = 0; c < 4; c++) {
      const int g = tid + c * 256;
      const int row = g >> 3;
      const int ch = g & 7;
      const int pos = ((ch ^ (row & 7)) * 8);
      {
        const float* ga = X + (size_t)(bm * 128 + row) * KD + k0 + ch * 8;
        float4 f0 = *(const float4*)(ga);
        float4 f1 = *(const float4*)(ga + 4);
        union { unsigned short u[8]; short8v v; } pk2;
        pk2.u[0] = f2bf(f0.x); pk2.u[1] = f2bf(f0.y);
        pk2.u[2] = f2bf(f0.z); pk2.u[3] = f2bf(f0.w);
        pk2.u[4] = f2bf(f1.x); pk2.u[5] = f2bf(f1.y);
        pk2.u[6] = f2bf(f1.z); pk2.u[7] = f2bf(f1.w);
        *reinterpret_cast<short8v*>(&As[row * 64 + pos]) = pk2.v;
      }
      {
        const float* gb = W + (size_t)row * KD + k0 + ch * 8;
        float4 f0 = *(const float4*)(gb);
        float4 f1 = *(const float4*)(gb + 4);
        union { unsigned short u[8]; short8v v; } pk2;
        pk2.u[0] = f2bf(f0.x); pk2.u[1] = f2bf(f0.y);
        pk2.u[2] = f2bf(f0.z); pk2.u[3] = f2bf(f0.w);
        pk2.u[4] = f2bf(f1.x); pk2.u[5] = f2bf(f1.y);
        pk2.u[6] = f2bf(f1.z); pk2.u[7] = f2bf(f1.w);
        *reinterpret_cast<short8v*>(&Bs[row * 64 + pos]) = pk2.v;
      }
    }
    __syncthreads();
#pragma unroll
    for (int kk = 0; kk < 2; kk++) {
      const int ch = kk * 4 + (lane >> 4);
      short8v a[4], b[4];
#pragma unroll
      for (int i = 0; i < 4; i++) {
        const int ar = wr * 64 + i * 16 + (lane & 15);
        a[i] = *reinterpret_cast<const short8v*>(&As[ar * 64 + ((ch ^ (ar & 7)) * 8)]);
        const int br = wc * 64 + i * 16 + (lane & 15);
        b[i] = *reinterpret_cast<const short8v*>(&Bs[br * 64 + ((ch ^ (br & 7)) * 8)]);
      }
#pragma unroll
      for (int i = 0; i < 4; i++)
#pragma unroll
        for (int j = 0; j < 4; j++)
          acc[i][j] = __builtin_amdgcn_mfma_f32_16x16x32_bf16(a[i], b[j], acc[i][j], 0, 0, 0);
    }
  }
#pragma unroll
  for (int i = 0; i < 4; i++)
#pragma unroll
    for (int j = 0; j < 4; j++)
#pragma unroll
      for (int r = 0; r < 4; r++) {
        const int row = bm * 128 + wr * 64 + i * 16 + (lane >> 4) * 4 + r;
        const int col = bn * 128 + wc * 64 + j * 16 + (lane & 15);
        C[(size_t)row * PSTRIDE + col] = acc[i][j][r];
      }
}

// ---------------------------------------------------------------------------
// k-normalization pre-pass: proj[row][0:128] <- k / (||k|| + eps).
// ---------------------------------------------------------------------------
__global__ __launch_bounds__(256) void norm_k(float* __restrict__ proj) {
  const int lane = threadIdx.x & 63;
  const int wid = (blockIdx.x * 256 + threadIdx.x) >> 6;
  float* rowp = proj + (size_t)wid * PSTRIDE;
  float2 kv = *reinterpret_cast<float2*>(rowp + lane * 2);
  float ss = kv.x * kv.x + kv.y * kv.y;
  ss += __shfl_xor(ss, 1);
  ss += __shfl_xor(ss, 2);
  ss += __shfl_xor(ss, 4);
  ss += __shfl_xor(ss, 8);
  ss += __shfl_xor(ss, 16);
  ss += __shfl_xor(ss, 32);
  const float rn = 1.0f / (sqrtf(ss) + 1e-6f);
  kv.x *= rn; kv.y *= rn;
  *reinterpret_cast<float2*>(rowp + lane * 2) = kv;
}

// ---------------------------------------------------------------------------
// Sequential scan, pure-register, zero LDS.
// One wave per (batch, 8-row group); 256 single-wave blocks.
// Lane mapping: col-block c = lane bits{0,1,3}, local row = bits{2,4,5}.
//   -> 8-lane reductions are xor1 (quad_perm 0xB1), xor2 (quad_perm 0x4E),
//      xor8 (row_ror:8 = 0x128): ALL DPP, no LDS ops in the step.
// Depth-4 register prefetch ring (A..D), fenced with sched_barrier(0) so the
// loads cannot be sunk to their uses (R2's failure); compiler emits exact
// counted vmcnt waits. silu+store tail of step t is deferred to slot t+1
// (off the recurrence chain).
// ---------------------------------------------------------------------------
__device__ __forceinline__ float sum8d(float v) {
  v += __int_as_float(__builtin_amdgcn_update_dpp(0, __float_as_int(v), 0xB1, 0xF, 0xF, true));   // xor 1
  v += __int_as_float(__builtin_amdgcn_update_dpp(0, __float_as_int(v), 0x4E, 0xF, 0xF, true));   // xor 2
  v += __int_as_float(__builtin_amdgcn_update_dpp(0, __float_as_int(v), 0x128, 0xF, 0xF, true));  // row_ror:8 == xor 8
  return v;
}

struct Buf { f32x4 kn[4]; f32x4 q[4]; float v, bx; };

__device__ __forceinline__ void load_buf(const float* __restrict__ p, int c, int row, Buf& b) {
  const f32x4* p4 = reinterpret_cast<const f32x4*>(p);
#pragma unroll
  for (int j = 0; j < 4; j++) b.kn[j] = p4[c * 4 + j];
#pragma unroll
  for (int j = 0; j < 4; j++) b.q[j] = p4[64 + c * 4 + j];
  b.v = p[128 + row];
  b.bx = p[384 + row];
}

__device__ __forceinline__ float core(const Buf& b, float db, float bb, f32x4 S4[4]) {
  f32x4 a0 = S4[0] * b.kn[0];
  f32x4 a1 = S4[1] * b.kn[1];
  a0 = __builtin_elementwise_fma(S4[2], b.kn[2], a0);
  a1 = __builtin_elementwise_fma(S4[3], b.kn[3], a1);
  const f32x4 acc = a0 + a1;
  const float r = sum8d((acc.x + acc.y) + (acc.z + acc.w));
  const float lg = fmaf(db, r, b.bx + bb);
  const float beta = __builtin_amdgcn_rcpf(1.0f + __expf(-lg));
  const float cr = beta * (b.v - r);
  const f32x4 cr4 = {cr, cr, cr, cr};
#pragma unroll
  for (int j = 0; j < 4; j++) S4[j] = __builtin_elementwise_fma(cr4, b.kn[j], S4[j]);
  f32x4 o0 = S4[0] * b.q[0];
  f32x4 o1 = S4[1] * b.q[1];
  o0 = __builtin_elementwise_fma(S4[2], b.q[2], o0);
  o1 = __builtin_elementwise_fma(S4[3], b.q[3], o1);
  const f32x4 ao = o0 + o1;
  return sum8d((ao.x + ao.y) + (ao.z + ao.w));     // raw od; silu deferred
}

__device__ __forceinline__ float fin(float od) {
  return od * od * __builtin_amdgcn_rcpf(1.0f + __expf(-od));
}

__global__ __launch_bounds__(64) void scan_kernel(
    const float* __restrict__ proj, const float* __restrict__ S_in,
    const float* __restrict__ d_beta, const float* __restrict__ b_beta,
    float* __restrict__ out, float* __restrict__ S_out)
{
  const int lane = threadIdx.x & 63;
  const int batch = blockIdx.x & 15;       // batches b, b+8 share XCD b%8
  const int wv = blockIdx.x >> 4;
  const int c = (lane & 3) | ((lane & 8) >> 1);                    // bits {0,1,3}
  const int rloc = ((lane >> 2) & 1) | (((lane >> 4) & 3) << 1);   // bits {2,4,5}
  const int row = wv * 8 + rloc;
  const bool w0 = ((lane & 11) == 0);      // c == 0: one lane per row stores

  f32x4 S4[4];
  {
    const f32x4* Sp4 = reinterpret_cast<const f32x4*>(
        S_in + ((size_t)batch * ND + row) * ND + c * 16);
#pragma unroll
    for (int j = 0; j < 4; j++) S4[j] = Sp4[j];
  }
  const float db = d_beta[row];
  const float bb = b_beta[row];

  const float* pb = proj + (size_t)batch * PSTRIDE;
  const size_t sstep = (size_t)NB * PSTRIDE;
  float* outp = out + (size_t)batch * ND + row;
  const size_t ostep = (size_t)NB * ND;

  Buf A, B, C, D;
  __builtin_amdgcn_sched_barrier(0);
  load_buf(pb + 0 * sstep, c, row, A);
  load_buf(pb + 1 * sstep, c, row, B);
  load_buf(pb + 2 * sstep, c, row, C);
  load_buf(pb + 3 * sstep, c, row, D);
  __builtin_amdgcn_sched_barrier(0);

  float od_prev;

#define SLOT(BUF, tnext)                                                  \
  do {                                                                    \
    const float gprev = fin(od_prev);                                     \
    if (w0) *outp = gprev;                                                \
    outp += ostep;                                                        \
    od_prev = core(BUF, db, bb, S4);                                      \
    __builtin_amdgcn_sched_barrier(0);                                    \
    load_buf(pb + (size_t)(tnext) * sstep, c, row, BUF);                  \
    __builtin_amdgcn_sched_barrier(0);                                    \
  } while (0)

  // peel: step 0 has no pending store
  od_prev = core(A, db, bb, S4);
  __builtin_amdgcn_sched_barrier(0);
  load_buf(pb + 4 * sstep, c, row, A);
  __builtin_amdgcn_sched_barrier(0);
  SLOT(B, 5);
  SLOT(C, 6);
  SLOT(D, 7);

  for (int t = 4; t < T_STEPS; t += 4) {
    const int t4 = (t + 4 < T_STEPS) ? t + 4 : T_STEPS - 1;
    const int t5 = (t + 5 < T_STEPS) ? t + 5 : T_STEPS - 1;
    const int t6 = (t + 6 < T_STEPS) ? t + 6 : T_STEPS - 1;
    const int t7 = (t + 7 < T_STEPS) ? t + 7 : T_STEPS - 1;
    SLOT(A, t4);
    SLOT(B, t5);
    SLOT(C, t6);
    SLOT(D, t7);
  }
  // final pending store (step 2047)
  {
    const float g = fin(od_prev);
    if (w0) *outp = g;
  }
#undef SLOT

  {
    f32x4* So4 = reinterpret_cast<f32x4*>(
        S_out + ((size_t)batch * ND + row) * ND + c * 16);
#pragma unroll
    for (int j = 0; j < 4; j++) So4[j] = S4[j];
  }
}

extern "C" void kernel_launch(void* const* d_in, const int* in_sizes, int n_in,
                              void* d_out, int out_size, void* d_ws, size_t ws_size,
                              hipStream_t stream) {
  const float* x  = (const float*)d_in[0];   // [2048][16][1024]
  const float* S0 = (const float*)d_in[1];   // [16][128][128]
  const float* Wk = (const float*)d_in[2];
  const float* Wv = (const float*)d_in[3];
  const float* Wq = (const float*)d_in[4];
  const float* Wb = (const float*)d_in[5];
  const float* db = (const float*)d_in[6];
  const float* bb = (const float*)d_in[7];
  float* out  = (float*)d_out;                           // [2048][16][128]
  float* Sout = out + (size_t)T_STEPS * NB * ND;         // [16][128][128]
  float* proj = (float*)d_ws;                            // [32768][512] = 64 MB

  dim3 ggrid(256, 4);
  proj_gemm<<<ggrid, 256, 0, stream>>>(x, Wk, Wv, Wq, Wb, proj);
  norm_k<<<8192, 256, 0, stream>>>(proj);
  scan_kernel<<<256, 64, 0, stream>>>(proj, S0, db, bb, out, Sout);
}